// Round 3
// baseline (304.824 us; speedup 1.0000x reference)
//
#include <hip/hip_runtime.h>
#include <hip/hip_bf16.h>

// Problem sizes (fixed)
#define B_    8
#define C_    256
#define NPIX  16384           // 128*128
#define KC2   32              // K-chunks for gram
#define KCH2  (NPIX / KC2)    // 512 k per block
#define BK    64
#define NSTEP (KCH2 / BK)     // 8 steps per block

typedef __attribute__((ext_vector_type(8))) short bf16x8;
typedef __attribute__((ext_vector_type(4))) float f32x4;
typedef unsigned int uint_;

__device__ __forceinline__ unsigned short f2bf(float x) {
  unsigned int u = __builtin_bit_cast(unsigned int, x);
  u = (u + 0x7fffu + ((u >> 16) & 1u)) >> 16;   // RTNE
  return (unsigned short)u;
}

// Pack 8 floats -> hi (RTZ bf16x8 as uint4) and lo (residual bf16x8 as uint4)
__device__ __forceinline__ void pack_hilo(const float4 a, const float4 b,
                                          uint4& hi, uint4& lo) {
  const float f[8] = {a.x, a.y, a.z, a.w, b.x, b.y, b.z, b.w};
  uint_ h[4], l[4];
#pragma unroll
  for (int i = 0; i < 4; ++i) {
    const uint_ u0 = __builtin_bit_cast(uint_, f[2 * i]);
    const uint_ u1 = __builtin_bit_cast(uint_, f[2 * i + 1]);
    h[i] = (u0 >> 16) | (u1 & 0xffff0000u);
    const float h0 = __builtin_bit_cast(float, u0 & 0xffff0000u);
    const float h1 = __builtin_bit_cast(float, u1 & 0xffff0000u);
    const uint_ l0 = __builtin_bit_cast(uint_, f[2 * i] - h0);
    const uint_ l1 = __builtin_bit_cast(uint_, f[2 * i + 1] - h1);
    l[i] = (l0 >> 16) | (l1 & 0xffff0000u);
  }
  hi = make_uint4(h[0], h[1], h[2], h[3]);
  lo = make_uint4(l[0], l[1], l[2], l[3]);
}

// ---------------- k0: zero G ----------------
__global__ __launch_bounds__(256) void k_zero(float* __restrict__ g) {
  const size_t i = ((size_t)blockIdx.x * 256 + threadIdx.x) * 4;
  *reinterpret_cast<float4*>(g + i) = make_float4(0.f, 0.f, 0.f, 0.f);
}

// ---------------- k_gram: G[b] += X_chunk X_chunk^T (split-bf16 3-pass) -----
// grid 256 = b(8) x kc(32); 512 thr (8 waves, 2x4 grid of 128x64 tiles)
// Staging is LANE-CONTIGUOUS: per j, a wave reads 8 rows x 256B (16 full
// lines/instr) instead of 32-64 scattered lines/instr (the round-2 killer).
__global__ __launch_bounds__(512, 2) void k_gram(const float* __restrict__ x,
                                                 float* __restrict__ G,
                                                 float* __restrict__ spart) {
  const int bid = blockIdx.x;
  const int kc = bid & (KC2 - 1);
  const int b  = bid >> 5;
  const float* X = x + (size_t)b * C_ * NPIX + kc * KCH2;

  __shared__ __align__(16) unsigned short Hi[2][256 * 64];   // 2 x 32 KB
  __shared__ __align__(16) unsigned short Lo[2][256 * 64];   // 2 x 32 KB

  const int tid  = threadIdx.x;
  const int lane = tid & 63;
  const int w    = tid >> 6;
  const int wr   = w >> 2;        // 0..1  (row block of 128)
  const int wc   = w & 3;         // 0..3  (col block of 64)

  // staging coords: row = srow + j*8 (j=0..3), cols scol..scol+7 (of 64)
  const int srow = w * 32 + (lane >> 3);
  const int scol = (lane & 7) * 8;
  const float* sp = X + (size_t)srow * NPIX + scol;

  float rs[4] = {0.f, 0.f, 0.f, 0.f};
  float4 g[8];                      // per j: g[2j], g[2j+1]

  // prologue: stage step 0
#pragma unroll
  for (int j = 0; j < 4; ++j) {
    g[2 * j]     = *reinterpret_cast<const float4*>(sp + (size_t)j * 8 * NPIX);
    g[2 * j + 1] = *reinterpret_cast<const float4*>(sp + (size_t)j * 8 * NPIX + 4);
  }
#pragma unroll
  for (int j = 0; j < 4; ++j) {
    rs[j] += (g[2*j].x + g[2*j].y) + (g[2*j].z + g[2*j].w) +
             (g[2*j+1].x + g[2*j+1].y) + (g[2*j+1].z + g[2*j+1].w);
    uint4 hi, lo;
    pack_hilo(g[2*j], g[2*j+1], hi, lo);
    const int idx = ((srow + j * 8) * 64 + scol) ^ ((srow & 7) << 3);
    *reinterpret_cast<uint4*>(&Hi[0][idx]) = hi;
    *reinterpret_cast<uint4*>(&Lo[0][idx]) = lo;
  }
  __syncthreads();

  f32x4 acc[8][4] = {};

  for (int ks = 0; ks < NSTEP; ++ks) {
    const int cur = ks & 1;
    if (ks + 1 < NSTEP) {
      const float* s2 = sp + (ks + 1) * BK;
#pragma unroll
      for (int j = 0; j < 4; ++j) {
        g[2 * j]     = *reinterpret_cast<const float4*>(s2 + (size_t)j * 8 * NPIX);
        g[2 * j + 1] = *reinterpret_cast<const float4*>(s2 + (size_t)j * 8 * NPIX + 4);
      }
    }
    // ---- MFMA phase on buf[cur] ----
    __builtin_amdgcn_s_setprio(1);
#pragma unroll
    for (int kk = 0; kk < 2; ++kk) {
      const int kb = kk * 32 + (lane >> 4) * 8;
      bf16x8 ahi[8], bhi[4], blo[4];
#pragma unroll
      for (int m = 0; m < 8; ++m) {
        const int row = wr * 128 + m * 16 + (lane & 15);
        ahi[m] = *reinterpret_cast<const bf16x8*>(&Hi[cur][(row * 64 + kb) ^ ((row & 7) << 3)]);
      }
#pragma unroll
      for (int n = 0; n < 4; ++n) {
        const int row = wc * 64 + n * 16 + (lane & 15);
        bhi[n] = *reinterpret_cast<const bf16x8*>(&Hi[cur][(row * 64 + kb) ^ ((row & 7) << 3)]);
      }
#pragma unroll
      for (int m = 0; m < 8; ++m)
#pragma unroll
        for (int n = 0; n < 4; ++n)
          acc[m][n] = __builtin_amdgcn_mfma_f32_16x16x32_bf16(ahi[m], bhi[n], acc[m][n], 0, 0, 0);
#pragma unroll
      for (int n = 0; n < 4; ++n) {
        const int row = wc * 64 + n * 16 + (lane & 15);
        blo[n] = *reinterpret_cast<const bf16x8*>(&Lo[cur][(row * 64 + kb) ^ ((row & 7) << 3)]);
      }
#pragma unroll
      for (int m = 0; m < 8; ++m)
#pragma unroll
        for (int n = 0; n < 4; ++n)
          acc[m][n] = __builtin_amdgcn_mfma_f32_16x16x32_bf16(ahi[m], blo[n], acc[m][n], 0, 0, 0);
#pragma unroll
      for (int m = 0; m < 8; ++m) {
        const int row = wr * 128 + m * 16 + (lane & 15);
        bf16x8 alo = *reinterpret_cast<const bf16x8*>(&Lo[cur][(row * 64 + kb) ^ ((row & 7) << 3)]);
#pragma unroll
        for (int n = 0; n < 4; ++n)
          acc[m][n] = __builtin_amdgcn_mfma_f32_16x16x32_bf16(alo, bhi[n], acc[m][n], 0, 0, 0);
      }
    }
    __builtin_amdgcn_s_setprio(0);
    // ---- convert+stage step ks+1 into buf[cur^1] ----
    if (ks + 1 < NSTEP) {
#pragma unroll
      for (int j = 0; j < 4; ++j) {
        rs[j] += (g[2*j].x + g[2*j].y) + (g[2*j].z + g[2*j].w) +
                 (g[2*j+1].x + g[2*j+1].y) + (g[2*j+1].z + g[2*j+1].w);
        uint4 hi, lo;
        pack_hilo(g[2*j], g[2*j+1], hi, lo);
        const int idx = ((srow + j * 8) * 64 + scol) ^ ((srow & 7) << 3);
        *reinterpret_cast<uint4*>(&Hi[cur ^ 1][idx]) = hi;
        *reinterpret_cast<uint4*>(&Lo[cur ^ 1][idx]) = lo;
      }
    }
    __syncthreads();
  }

  // rowsum partials: reduce over the 8 lanes sharing a row
#pragma unroll
  for (int j = 0; j < 4; ++j) {
#pragma unroll
    for (int off = 1; off < 8; off <<= 1) rs[j] += __shfl_xor(rs[j], off, 64);
  }
  if ((lane & 7) == 0) {
#pragma unroll
    for (int j = 0; j < 4; ++j)
      spart[((size_t)b * KC2 + kc) * 256 + srow + j * 8] = rs[j];
  }

  // atomic accumulate into G[b]
  float* Gb = G + (size_t)b * 65536;
#pragma unroll
  for (int m = 0; m < 8; ++m) {
    const int row0 = wr * 128 + m * 16 + ((lane >> 4) << 2);
#pragma unroll
    for (int n = 0; n < 4; ++n) {
      const int col = wc * 64 + n * 16 + (lane & 15);
#pragma unroll
      for (int j = 0; j < 4; ++j)
        atomicAdd(&Gb[(size_t)(row0 + j) * C_ + col], acc[m][n][j]);
    }
  }
}

// ---------------- k4: 256x256 transpose (w2 -> w2t) ----------------
__global__ __launch_bounds__(256) void k_transpose(const float* __restrict__ in,
                                                   float* __restrict__ outp) {
  __shared__ float t[32][33];
  const int bx = blockIdx.x & 7, by = blockIdx.x >> 3;
  const int tx = threadIdx.x & 31, ty = threadIdx.x >> 5;
#pragma unroll
  for (int i = 0; i < 32; i += 8)
    t[ty + i][tx] = in[(size_t)(by * 32 + ty + i) * 256 + bx * 32 + tx];
  __syncthreads();
#pragma unroll
  for (int i = 0; i < 32; i += 8)
    outp[(size_t)(bx * 32 + ty + i) * 256 + by * 32 + tx] = t[tx][ty + i];
}

// ---------------- k_u: s = reduce(spart); u1 = W1 s, u2 = W2 s ----------------
__global__ __launch_bounds__(256) void k_u(const float* __restrict__ w1,
                                           const float* __restrict__ w2,
                                           const float* __restrict__ spart,
                                           float* __restrict__ u1,
                                           float* __restrict__ u2) {
  const int b = blockIdx.x;
  const int tid = threadIdx.x;
  __shared__ float sl[256];
  float sv = 0.f;
#pragma unroll 8
  for (int kc = 0; kc < KC2; ++kc) sv += spart[((size_t)b * KC2 + kc) * 256 + tid];
  sl[tid] = sv;
  __syncthreads();
  float a1 = 0.f, a2 = 0.f;
#pragma unroll 4
  for (int c = 0; c < 256; ++c) {
    a1 += w1[(size_t)tid * 256 + c] * sl[c];
    a2 += w2[(size_t)tid * 256 + c] * sl[c];
  }
  u1[b * 256 + tid] = a1;
  u2[b * 256 + tid] = a2;
}

// ---------------- k_smallmm: C[i,j] = sum_k A[i,k] B[k,j] (256^3) ----------
__global__ __launch_bounds__(256) void k_smallmm(const float* __restrict__ A, long asb,
                                                 const float* __restrict__ Bm, long bsb,
                                                 float* __restrict__ Cm, long csb) {
  const int b  = blockIdx.y;
  const int i0 = blockIdx.x * 8;
  const float* Ab = A  + (size_t)asb * b;
  const float* Bb = Bm + (size_t)bsb * b;
  float*       Cb = Cm + (size_t)csb * b;
  const int tid = threadIdx.x;
  __shared__ float arows[8][256];
#pragma unroll
  for (int rr = 0; rr < 8; ++rr) arows[rr][tid] = Ab[(size_t)(i0 + rr) * 256 + tid];
  __syncthreads();
  float acc[8] = {};
#pragma unroll 4
  for (int k = 0; k < 256; ++k) {
    const float bv = Bb[(size_t)k * 256 + tid];
#pragma unroll
    for (int rr = 0; rr < 8; ++rr) acc[rr] += arows[rr][k] * bv;
  }
#pragma unroll
  for (int rr = 0; rr < 8; ++rr) Cb[(size_t)(i0 + rr) * 256 + tid] = acc[rr];
}

// ---------------- k_softmax: logits finish + row softmax -> A (bf16) --------
__global__ __launch_bounds__(256) void k_softmax(const float* __restrict__ L,
                                                 const float* __restrict__ b1,
                                                 const float* __restrict__ b2,
                                                 const float* __restrict__ u1,
                                                 const float* __restrict__ u2,
                                                 unsigned short* __restrict__ Abf) {
  const int b = blockIdx.y, i = blockIdx.x, j = threadIdx.x;
  const size_t base = ((size_t)b * 256 + i) * 256;
  const float v = L[base + j] + u1[b * 256 + i] * b2[j] +
                  b1[i] * (u2[b * 256 + j] + 16384.f * b2[j]);
  const int lane = j & 63, wv = j >> 6;
  __shared__ float redm[4], reds[4];
  float m = v;
#pragma unroll
  for (int off = 32; off; off >>= 1) m = fmaxf(m, __shfl_xor(m, off, 64));
  if (lane == 0) redm[wv] = m;
  __syncthreads();
  m = fmaxf(fmaxf(redm[0], redm[1]), fmaxf(redm[2], redm[3]));
  const float e = __expf(v - m);
  float sm = e;
#pragma unroll
  for (int off = 32; off; off >>= 1) sm += __shfl_xor(sm, off, 64);
  if (lane == 0) reds[wv] = sm;
  __syncthreads();
  sm = (reds[0] + reds[1]) + (reds[2] + reds[3]);
  Abf[base + j] = f2bf(e / sm);
}

// ---------------- k_av: out = x + A @ X  (A-frags from L2, kk-pipelined) ----
// grid 2048 = n-tile(256) x b(8, low bits -> XCD-pinned); 512 thr (8 waves)
__global__ __launch_bounds__(512, 4) void k_av(const unsigned short* __restrict__ Abf,
                                               const float* __restrict__ x,
                                               float* __restrict__ out) {
  const int bx = blockIdx.x;
  const int b  = bx & 7;
  const int n0 = (bx >> 3) * 64;
  const unsigned short* Ab = Abf + (size_t)b * 65536;
  const float* Xb = x   + (size_t)b * C_ * NPIX;
  float*       Ob = out + (size_t)b * C_ * NPIX;

  __shared__ __align__(16) unsigned short Xt[64 * 256];   // [n][d] swizzled, 32 KB

  const int tid = threadIdx.x;
  const int lane = tid & 63, w = tid >> 6;
  const int wc2 = w >> 1, wn = w & 1;

  // stage X^T (bf16, RTNE) once: two 4x4 blocks per thread
#pragma unroll
  for (int h = 0; h < 2; ++h) {
    const int d  = (tid >> 4) * 4 + h * 128;
    const int nn = (tid & 15) * 4;
    const float* xs = Xb + (size_t)d * NPIX + n0 + nn;
    float4 r0 = *reinterpret_cast<const float4*>(xs);
    float4 r1 = *reinterpret_cast<const float4*>(xs + NPIX);
    float4 r2 = *reinterpret_cast<const float4*>(xs + 2 * NPIX);
    float4 r3 = *reinterpret_cast<const float4*>(xs + 3 * NPIX);
    ushort4 c0 = make_ushort4(f2bf(r0.x), f2bf(r1.x), f2bf(r2.x), f2bf(r3.x));
    ushort4 c1 = make_ushort4(f2bf(r0.y), f2bf(r1.y), f2bf(r2.y), f2bf(r3.y));
    ushort4 c2 = make_ushort4(f2bf(r0.z), f2bf(r1.z), f2bf(r2.z), f2bf(r3.z));
    ushort4 c3 = make_ushort4(f2bf(r0.w), f2bf(r1.w), f2bf(r2.w), f2bf(r3.w));
    const int i0 = ((nn + 0) * 256 + d) ^ (((nn + 0) & 7) << 3);
    const int i1 = ((nn + 1) * 256 + d) ^ (((nn + 1) & 7) << 3);
    const int i2 = ((nn + 2) * 256 + d) ^ (((nn + 2) & 7) << 3);
    const int i3 = ((nn + 3) * 256 + d) ^ (((nn + 3) & 7) << 3);
    *reinterpret_cast<ushort4*>(&Xt[i0]) = c0;
    *reinterpret_cast<ushort4*>(&Xt[i1]) = c1;
    *reinterpret_cast<ushort4*>(&Xt[i2]) = c2;
    *reinterpret_cast<ushort4*>(&Xt[i3]) = c3;
  }
  __syncthreads();

  f32x4 acc[4][2] = {};
  bf16x8 af0[4], af1[4];
  bf16x8 bq0[2], bq1[2];

#define LOADFR(kk, af, bq)                                                    \
  {                                                                           \
    const int kb = (kk) * 32 + (lane >> 4) * 8;                               \
    _Pragma("unroll")                                                         \
    for (int m = 0; m < 4; ++m) {                                             \
      const int c = wc2 * 64 + m * 16 + (lane & 15);                          \
      uint4 v = *reinterpret_cast<const uint4*>(Ab + (size_t)c * 256 + kb);   \
      af[m] = __builtin_bit_cast(bf16x8, v);                                  \
    }                                                                         \
    _Pragma("unroll")                                                         \
    for (int n = 0; n < 2; ++n) {                                             \
      const int nn2 = wn * 32 + n * 16 + (lane & 15);                         \
      bq[n] = *reinterpret_cast<const bf16x8*>(&Xt[(nn2 * 256 + kb) ^ ((nn2 & 7) << 3)]); \
    }                                                                         \
  }
#define MFMA8(af, bq)                                                         \
  _Pragma("unroll")                                                           \
  for (int m = 0; m < 4; ++m)                                                 \
    _Pragma("unroll")                                                         \
    for (int n = 0; n < 2; ++n)                                               \
      acc[m][n] = __builtin_amdgcn_mfma_f32_16x16x32_bf16(af[m], bq[n], acc[m][n], 0, 0, 0);

  LOADFR(0, af0, bq0)
#pragma unroll
  for (int kk = 0; kk < 8; kk += 2) {
    if (kk + 1 < 8) LOADFR(kk + 1, af1, bq1)
    MFMA8(af0, bq0)
    if (kk + 2 < 8) LOADFR(kk + 2, af0, bq0)
    MFMA8(af1, bq1)
  }
#undef LOADFR
#undef MFMA8

  // epilogue: out = x + acc (x re-read is L2-hot: same 64 KB staged above)
#pragma unroll
  for (int m = 0; m < 4; ++m) {
    const int row0 = wc2 * 64 + m * 16 + ((lane >> 4) << 2);
#pragma unroll
    for (int n = 0; n < 2; ++n) {
      const int col = n0 + wn * 32 + n * 16 + (lane & 15);
#pragma unroll
      for (int j = 0; j < 4; ++j) {
        const size_t a = (size_t)(row0 + j) * NPIX + col;
        Ob[a] = Xb[a] + acc[m][n][j];
      }
    }
  }
}

extern "C" void kernel_launch(void* const* d_in, const int* in_sizes, int n_in,
                              void* d_out, int out_size, void* d_ws, size_t ws_size,
                              hipStream_t stream) {
  const float* x  = (const float*)d_in[0];
  const float* w1 = (const float*)d_in[1];
  const float* b1 = (const float*)d_in[2];
  const float* w2 = (const float*)d_in[3];
  const float* b2 = (const float*)d_in[4];
  float* out = (float*)d_out;
  char* ws = (char*)d_ws;

  constexpr size_t G_OFF     = 0;                                   // 2 MB
  constexpr size_t T1_OFF    = G_OFF   + (size_t)B_ * C_ * C_ * 4;  // 2 MB
  constexpr size_t L_OFF     = T1_OFF  + (size_t)B_ * C_ * C_ * 4;  // 2 MB
  constexpr size_t W2T_OFF   = L_OFF   + (size_t)B_ * C_ * C_ * 4;  // 256 KB
  constexpr size_t SPART_OFF = W2T_OFF + (size_t)C_ * C_ * 4;       // 256 KB
  constexpr size_t U1_OFF    = SPART_OFF + (size_t)B_ * KC2 * C_ * 4;
  constexpr size_t U2_OFF    = U1_OFF  + (size_t)B_ * C_ * 4;
  constexpr size_t ABF_OFF   = U2_OFF  + (size_t)B_ * C_ * 4;       // 1 MB

  float* G     = (float*)(ws + G_OFF);
  float* T1    = (float*)(ws + T1_OFF);
  float* L     = (float*)(ws + L_OFF);
  float* w2t   = (float*)(ws + W2T_OFF);
  float* spart = (float*)(ws + SPART_OFF);
  float* u1    = (float*)(ws + U1_OFF);
  float* u2    = (float*)(ws + U2_OFF);
  unsigned short* Abf = (unsigned short*)(ws + ABF_OFF);

  k_zero     <<<(B_ * C_ * C_) / 1024, 256, 0, stream>>>(G);
  k_transpose<<<64, 256, 0, stream>>>(w2, w2t);
  k_gram     <<<B_ * KC2, 512, 0, stream>>>(x, G, spart);
  k_u        <<<B_, 256, 0, stream>>>(w1, w2, spart, u1, u2);
  k_smallmm  <<<dim3(32, B_), 256, 0, stream>>>(w1, 0, G, C_ * C_, T1, C_ * C_);
  k_smallmm  <<<dim3(32, B_), 256, 0, stream>>>(T1, C_ * C_, w2t, 0, L, C_ * C_);
  k_softmax  <<<dim3(C_, B_), 256, 0, stream>>>(L, b1, b2, u1, u2, Abf);
  k_av       <<<dim3(NPIX / 64 * B_), 512, 0, stream>>>(Abf, x, out);
}

// Round 4
// 235.080 us; speedup vs baseline: 1.2967x; 1.2967x over previous
//
#include <hip/hip_runtime.h>
#include <hip/hip_bf16.h>

// Problem sizes (fixed)
#define B_    8
#define C_    256
#define NPIX  16384           // 128*128
#define BK    64
#define KC4   16              // K-chunks for gram
#define KCH4  (NPIX / KC4)    // 1024 k per block
#define NSTEP4 (KCH4 / BK)    // 16 steps per block

typedef __attribute__((ext_vector_type(8))) short bf16x8;
typedef __attribute__((ext_vector_type(4))) float f32x4;
typedef unsigned int uint_;

__device__ __forceinline__ unsigned short f2bf(float x) {
  unsigned int u = __builtin_bit_cast(unsigned int, x);
  u = (u + 0x7fffu + ((u >> 16) & 1u)) >> 16;   // RTNE
  return (unsigned short)u;
}

// ---------------- k_gram: partial Gram, NO atomics ----------------
// grid 256 = half(2) x b(8) x kc(16); bid = half*128 + b*16 + kc so the two
// halves sharing (b,kc) are 128 apart -> same XCD (128%8==0) for L2 reuse.
// 512 thr / 8 waves (2x4), wave tile 64x64 over a 128x256 output block.
// Split-bf16 3-pass (hi/lo), double-buffered LDS, reg-staged prefetch.
// Epilogue: coalesced f32 partial store into gpart (= d_out scratch).
__global__ __launch_bounds__(512, 2) void k_gram(const float* __restrict__ x,
                                                 float* __restrict__ gpart,
                                                 float* __restrict__ spart) {
  const int bid  = blockIdx.x;
  const int half = bid >> 7;
  const int b    = (bid >> 4) & 7;
  const int kc   = bid & 15;
  const float* X = x + (size_t)b * C_ * NPIX + kc * KCH4;

  __shared__ __align__(16) unsigned short Hi[2][256 * 64];   // 2 x 32 KB
  __shared__ __align__(16) unsigned short Lo[2][256 * 64];   // 2 x 32 KB

  const int tid  = threadIdx.x;
  const int lane = tid & 63;
  const int w    = tid >> 6;
  const int wr   = w >> 2;        // 0..1  (row block of 64 within the 128-half)
  const int wc   = w & 3;         // 0..3  (col block of 64)

  // staging: row = j*32 + srow (j=0..7), cols scol..scol+3.
  // One load instr = 4 rows x 16 lanes x 16B = 16 FULL 64B lines.
  const int srow = tid >> 4;          // 0..31
  const int scol = (tid & 15) * 4;    // 0..60
  const float* sp = X + (size_t)srow * NPIX + scol;

  float rs[8] = {};
  float4 g[8];

#define GLOAD(ks)                                                             \
  _Pragma("unroll")                                                           \
  for (int j = 0; j < 8; ++j)                                                 \
    g[j] = *reinterpret_cast<const float4*>(sp + (size_t)j * 32 * NPIX + (ks) * BK);

#define STAGE(buf)                                                            \
  _Pragma("unroll")                                                           \
  for (int j = 0; j < 8; ++j) {                                               \
    const float4 v = g[j];                                                    \
    rs[j] += (v.x + v.y) + (v.z + v.w);                                       \
    const uint_ u0 = __builtin_bit_cast(uint_, v.x);                          \
    const uint_ u1 = __builtin_bit_cast(uint_, v.y);                          \
    const uint_ u2 = __builtin_bit_cast(uint_, v.z);                          \
    const uint_ u3 = __builtin_bit_cast(uint_, v.w);                          \
    uint2 hi, lo;                                                             \
    hi.x = (u0 >> 16) | (u1 & 0xffff0000u);                                   \
    hi.y = (u2 >> 16) | (u3 & 0xffff0000u);                                   \
    const float h0 = __builtin_bit_cast(float, u0 & 0xffff0000u);             \
    const float h1 = __builtin_bit_cast(float, u1 & 0xffff0000u);             \
    const float h2 = __builtin_bit_cast(float, u2 & 0xffff0000u);             \
    const float h3 = __builtin_bit_cast(float, u3 & 0xffff0000u);             \
    const uint_ l0 = __builtin_bit_cast(uint_, v.x - h0);                     \
    const uint_ l1 = __builtin_bit_cast(uint_, v.y - h1);                     \
    const uint_ l2 = __builtin_bit_cast(uint_, v.z - h2);                     \
    const uint_ l3 = __builtin_bit_cast(uint_, v.w - h3);                     \
    lo.x = (l0 >> 16) | (l1 & 0xffff0000u);                                   \
    lo.y = (l2 >> 16) | (l3 & 0xffff0000u);                                   \
    const int row = j * 32 + srow;                                            \
    const int idx = (row * 64 + scol) ^ ((row & 7) << 3);                     \
    *reinterpret_cast<uint2*>(&Hi[buf][idx]) = hi;                            \
    *reinterpret_cast<uint2*>(&Lo[buf][idx]) = lo;                            \
  }

  // prologue
  GLOAD(0)
  STAGE(0)
  __syncthreads();

  f32x4 acc[4][4] = {};

  for (int ks = 0; ks < NSTEP4; ++ks) {
    const int cur = ks & 1;
    if (ks + 1 < NSTEP4) GLOAD(ks + 1)
    // ---- MFMA phase on buf[cur] ----
    __builtin_amdgcn_s_setprio(1);
#pragma unroll
    for (int kk = 0; kk < 2; ++kk) {
      const int kb = kk * 32 + (lane >> 4) * 8;
      bf16x8 ahi[4], bhi[4], blo[4];
#pragma unroll
      for (int m = 0; m < 4; ++m) {
        const int row = half * 128 + wr * 64 + m * 16 + (lane & 15);
        ahi[m] = *reinterpret_cast<const bf16x8*>(&Hi[cur][(row * 64 + kb) ^ ((row & 7) << 3)]);
      }
#pragma unroll
      for (int n = 0; n < 4; ++n) {
        const int row = wc * 64 + n * 16 + (lane & 15);
        bhi[n] = *reinterpret_cast<const bf16x8*>(&Hi[cur][(row * 64 + kb) ^ ((row & 7) << 3)]);
      }
#pragma unroll
      for (int m = 0; m < 4; ++m)
#pragma unroll
        for (int n = 0; n < 4; ++n)
          acc[m][n] = __builtin_amdgcn_mfma_f32_16x16x32_bf16(ahi[m], bhi[n], acc[m][n], 0, 0, 0);
#pragma unroll
      for (int n = 0; n < 4; ++n) {
        const int row = wc * 64 + n * 16 + (lane & 15);
        blo[n] = *reinterpret_cast<const bf16x8*>(&Lo[cur][(row * 64 + kb) ^ ((row & 7) << 3)]);
      }
#pragma unroll
      for (int m = 0; m < 4; ++m)
#pragma unroll
        for (int n = 0; n < 4; ++n)
          acc[m][n] = __builtin_amdgcn_mfma_f32_16x16x32_bf16(ahi[m], blo[n], acc[m][n], 0, 0, 0);
#pragma unroll
      for (int m = 0; m < 4; ++m) {
        const int row = half * 128 + wr * 64 + m * 16 + (lane & 15);
        bf16x8 alo = *reinterpret_cast<const bf16x8*>(&Lo[cur][(row * 64 + kb) ^ ((row & 7) << 3)]);
#pragma unroll
        for (int n = 0; n < 4; ++n)
          acc[m][n] = __builtin_amdgcn_mfma_f32_16x16x32_bf16(alo, bhi[n], acc[m][n], 0, 0, 0);
      }
    }
    __builtin_amdgcn_s_setprio(0);
    // ---- convert+stage step ks+1 into buf[cur^1] ----
    if (ks + 1 < NSTEP4) STAGE(cur ^ 1)
    __syncthreads();
  }
#undef GLOAD
#undef STAGE

  // rowsum partials: 16 lanes share a row; only half==0 blocks write
#pragma unroll
  for (int j = 0; j < 8; ++j) {
#pragma unroll
    for (int off = 1; off < 16; off <<= 1) rs[j] += __shfl_xor(rs[j], off, 64);
  }
  if (half == 0 && (tid & 15) == 0) {
#pragma unroll
    for (int j = 0; j < 8; ++j)
      spart[((size_t)b * KC4 + kc) * 256 + j * 32 + srow] = rs[j];
  }

  // coalesced partial store: gpart[bid] is a 128x256 f32 block
  float* gp = gpart + (size_t)bid * (128 * 256);
#pragma unroll
  for (int m = 0; m < 4; ++m) {
    const int row0 = wr * 64 + m * 16 + ((lane >> 4) << 2);
#pragma unroll
    for (int n = 0; n < 4; ++n) {
      const int col = wc * 64 + n * 16 + (lane & 15);
#pragma unroll
      for (int j = 0; j < 4; ++j)
        gp[(size_t)(row0 + j) * 256 + col] = acc[m][n][j];
    }
  }
}

// ---------------- k_reduce: G = sum_kc partials (float4, coalesced) ---------
__global__ __launch_bounds__(256) void k_reduce(const float* __restrict__ gpart,
                                                float* __restrict__ G) {
  const int t  = blockIdx.x * 256 + threadIdx.x;   // 0..131071
  const int b  = t >> 14;
  const int i  = (t >> 6) & 255;
  const int j4 = (t & 63) * 4;
  const int hb = (i >> 7) * 128 + b * 16;          // partial block base (half,b)
  const int il = i & 127;
  float4 s = make_float4(0.f, 0.f, 0.f, 0.f);
#pragma unroll
  for (int kc = 0; kc < KC4; ++kc) {
    const float4 v = *reinterpret_cast<const float4*>(
        &gpart[(size_t)(hb + kc) * (128 * 256) + (size_t)il * 256 + j4]);
    s.x += v.x; s.y += v.y; s.z += v.z; s.w += v.w;
  }
  *reinterpret_cast<float4*>(&G[((size_t)b * 256 + i) * 256 + j4]) = s;
}

// ---------------- k_transpose: 256x256 (w2 -> w2t) ----------------
__global__ __launch_bounds__(256) void k_transpose(const float* __restrict__ in,
                                                   float* __restrict__ outp) {
  __shared__ float t[32][33];
  const int bx = blockIdx.x & 7, by = blockIdx.x >> 3;
  const int tx = threadIdx.x & 31, ty = threadIdx.x >> 5;
#pragma unroll
  for (int i = 0; i < 32; i += 8)
    t[ty + i][tx] = in[(size_t)(by * 32 + ty + i) * 256 + bx * 32 + tx];
  __syncthreads();
#pragma unroll
  for (int i = 0; i < 32; i += 8)
    outp[(size_t)(bx * 32 + ty + i) * 256 + by * 32 + tx] = t[tx][ty + i];
}

// ---------------- k_u: s = reduce(spart); u1 = W1 s, u2 = W2 s --------------
__global__ __launch_bounds__(256) void k_u(const float* __restrict__ w1,
                                           const float* __restrict__ w2,
                                           const float* __restrict__ spart,
                                           float* __restrict__ u1,
                                           float* __restrict__ u2) {
  const int b = blockIdx.x;
  const int tid = threadIdx.x;
  __shared__ float sl[256];
  float sv = 0.f;
#pragma unroll
  for (int kc = 0; kc < KC4; ++kc) sv += spart[((size_t)b * KC4 + kc) * 256 + tid];
  sl[tid] = sv;
  __syncthreads();
  float a1 = 0.f, a2 = 0.f;
#pragma unroll 4
  for (int c = 0; c < 256; ++c) {
    a1 += w1[(size_t)tid * 256 + c] * sl[c];
    a2 += w2[(size_t)tid * 256 + c] * sl[c];
  }
  u1[b * 256 + tid] = a1;
  u2[b * 256 + tid] = a2;
}

// ---------------- k_smallmm: C[i,j] = sum_k A[i,k] B[k,j] (256^3) ----------
__global__ __launch_bounds__(256) void k_smallmm(const float* __restrict__ A, long asb,
                                                 const float* __restrict__ Bm, long bsb,
                                                 float* __restrict__ Cm, long csb) {
  const int b  = blockIdx.y;
  const int i0 = blockIdx.x * 8;
  const float* Ab = A  + (size_t)asb * b;
  const float* Bb = Bm + (size_t)bsb * b;
  float*       Cb = Cm + (size_t)csb * b;
  const int tid = threadIdx.x;
  __shared__ float arows[8][256];
#pragma unroll
  for (int rr = 0; rr < 8; ++rr) arows[rr][tid] = Ab[(size_t)(i0 + rr) * 256 + tid];
  __syncthreads();
  float acc[8] = {};
#pragma unroll 4
  for (int k = 0; k < 256; ++k) {
    const float bv = Bb[(size_t)k * 256 + tid];
#pragma unroll
    for (int rr = 0; rr < 8; ++rr) acc[rr] += arows[rr][k] * bv;
  }
#pragma unroll
  for (int rr = 0; rr < 8; ++rr) Cb[(size_t)(i0 + rr) * 256 + tid] = acc[rr];
}

// ---------------- k_softmax: logits finish + row softmax -> A (bf16) --------
__global__ __launch_bounds__(256) void k_softmax(const float* __restrict__ L,
                                                 const float* __restrict__ b1,
                                                 const float* __restrict__ b2,
                                                 const float* __restrict__ u1,
                                                 const float* __restrict__ u2,
                                                 unsigned short* __restrict__ Abf) {
  const int b = blockIdx.y, i = blockIdx.x, j = threadIdx.x;
  const size_t base = ((size_t)b * 256 + i) * 256;
  const float v = L[base + j] + u1[b * 256 + i] * b2[j] +
                  b1[i] * (u2[b * 256 + j] + 16384.f * b2[j]);
  const int lane = j & 63, wv = j >> 6;
  __shared__ float redm[4], reds[4];
  float m = v;
#pragma unroll
  for (int off = 32; off; off >>= 1) m = fmaxf(m, __shfl_xor(m, off, 64));
  if (lane == 0) redm[wv] = m;
  __syncthreads();
  m = fmaxf(fmaxf(redm[0], redm[1]), fmaxf(redm[2], redm[3]));
  const float e = __expf(v - m);
  float sm = e;
#pragma unroll
  for (int off = 32; off; off >>= 1) sm += __shfl_xor(sm, off, 64);
  if (lane == 0) reds[wv] = sm;
  __syncthreads();
  sm = (reds[0] + reds[1]) + (reds[2] + reds[3]);
  Abf[base + j] = f2bf(e / sm);
}

// ---------------- k_av: out = x + A @ X  (A-frags from L2, kk-pipelined) ----
__global__ __launch_bounds__(512, 4) void k_av(const unsigned short* __restrict__ Abf,
                                               const float* __restrict__ x,
                                               float* __restrict__ out) {
  const int bx = blockIdx.x;
  const int b  = bx & 7;
  const int n0 = (bx >> 3) * 64;
  const unsigned short* Ab = Abf + (size_t)b * 65536;
  const float* Xb = x   + (size_t)b * C_ * NPIX;
  float*       Ob = out + (size_t)b * C_ * NPIX;

  __shared__ __align__(16) unsigned short Xt[64 * 256];   // [n][d] swizzled, 32 KB

  const int tid = threadIdx.x;
  const int lane = tid & 63, w = tid >> 6;
  const int wc2 = w >> 1, wn = w & 1;

  // stage X^T (bf16, RTNE) once: two 4x4 blocks per thread
#pragma unroll
  for (int h = 0; h < 2; ++h) {
    const int d  = (tid >> 4) * 4 + h * 128;
    const int nn = (tid & 15) * 4;
    const float* xs = Xb + (size_t)d * NPIX + n0 + nn;
    float4 r0 = *reinterpret_cast<const float4*>(xs);
    float4 r1 = *reinterpret_cast<const float4*>(xs + NPIX);
    float4 r2 = *reinterpret_cast<const float4*>(xs + 2 * NPIX);
    float4 r3 = *reinterpret_cast<const float4*>(xs + 3 * NPIX);
    ushort4 c0 = make_ushort4(f2bf(r0.x), f2bf(r1.x), f2bf(r2.x), f2bf(r3.x));
    ushort4 c1 = make_ushort4(f2bf(r0.y), f2bf(r1.y), f2bf(r2.y), f2bf(r3.y));
    ushort4 c2 = make_ushort4(f2bf(r0.z), f2bf(r1.z), f2bf(r2.z), f2bf(r3.z));
    ushort4 c3 = make_ushort4(f2bf(r0.w), f2bf(r1.w), f2bf(r2.w), f2bf(r3.w));
    const int i0 = ((nn + 0) * 256 + d) ^ (((nn + 0) & 7) << 3);
    const int i1 = ((nn + 1) * 256 + d) ^ (((nn + 1) & 7) << 3);
    const int i2 = ((nn + 2) * 256 + d) ^ (((nn + 2) & 7) << 3);
    const int i3 = ((nn + 3) * 256 + d) ^ (((nn + 3) & 7) << 3);
    *reinterpret_cast<ushort4*>(&Xt[i0]) = c0;
    *reinterpret_cast<ushort4*>(&Xt[i1]) = c1;
    *reinterpret_cast<ushort4*>(&Xt[i2]) = c2;
    *reinterpret_cast<ushort4*>(&Xt[i3]) = c3;
  }
  __syncthreads();

  f32x4 acc[4][2] = {};
  bf16x8 af0[4], af1[4];
  bf16x8 bq0[2], bq1[2];

#define LOADFR(kk, af, bq)                                                    \
  {                                                                           \
    const int kb = (kk) * 32 + (lane >> 4) * 8;                               \
    _Pragma("unroll")                                                         \
    for (int m = 0; m < 4; ++m) {                                             \
      const int c = wc2 * 64 + m * 16 + (lane & 15);                          \
      uint4 v = *reinterpret_cast<const uint4*>(Ab + (size_t)c * 256 + kb);   \
      af[m] = __builtin_bit_cast(bf16x8, v);                                  \
    }                                                                         \
    _Pragma("unroll")                                                         \
    for (int n = 0; n < 2; ++n) {                                             \
      const int nn2 = wn * 32 + n * 16 + (lane & 15);                         \
      bq[n] = *reinterpret_cast<const bf16x8*>(&Xt[(nn2 * 256 + kb) ^ ((nn2 & 7) << 3)]); \
    }                                                                         \
  }
#define MFMA8(af, bq)                                                         \
  _Pragma("unroll")                                                           \
  for (int m = 0; m < 4; ++m)                                                 \
    _Pragma("unroll")                                                         \
    for (int n = 0; n < 2; ++n)                                               \
      acc[m][n] = __builtin_amdgcn_mfma_f32_16x16x32_bf16(af[m], bq[n], acc[m][n], 0, 0, 0);

  LOADFR(0, af0, bq0)
#pragma unroll
  for (int kk = 0; kk < 8; kk += 2) {
    if (kk + 1 < 8) LOADFR(kk + 1, af1, bq1)
    MFMA8(af0, bq0)
    if (kk + 2 < 8) LOADFR(kk + 2, af0, bq0)
    MFMA8(af1, bq1)
  }
#undef LOADFR
#undef MFMA8

  // epilogue: out = x + acc (x re-read is L2-hot: same 64 KB staged above)
#pragma unroll
  for (int m = 0; m < 4; ++m) {
    const int row0 = wc2 * 64 + m * 16 + ((lane >> 4) << 2);
#pragma unroll
    for (int n = 0; n < 2; ++n) {
      const int col = n0 + wn * 32 + n * 16 + (lane & 15);
#pragma unroll
      for (int j = 0; j < 4; ++j) {
        const size_t a = (size_t)(row0 + j) * NPIX + col;
        Ob[a] = Xb[a] + acc[m][n][j];
      }
    }
  }
}

extern "C" void kernel_launch(void* const* d_in, const int* in_sizes, int n_in,
                              void* d_out, int out_size, void* d_ws, size_t ws_size,
                              hipStream_t stream) {
  const float* x  = (const float*)d_in[0];
  const float* w1 = (const float*)d_in[1];
  const float* b1 = (const float*)d_in[2];
  const float* w2 = (const float*)d_in[3];
  const float* b2 = (const float*)d_in[4];
  float* out = (float*)d_out;
  char* ws = (char*)d_ws;

  // Gram partials live in d_out (33.5 MB of its 64 MB) — consumed by k_reduce
  // before k_av overwrites d_out with the real output.
  float* gpart = out;

  constexpr size_t G_OFF     = 0;                                   // 2 MB
  constexpr size_t T1_OFF    = G_OFF   + (size_t)B_ * C_ * C_ * 4;  // 2 MB
  constexpr size_t L_OFF     = T1_OFF  + (size_t)B_ * C_ * C_ * 4;  // 2 MB
  constexpr size_t W2T_OFF   = L_OFF   + (size_t)B_ * C_ * C_ * 4;  // 256 KB
  constexpr size_t SPART_OFF = W2T_OFF + (size_t)C_ * C_ * 4;       // 128 KB
  constexpr size_t U1_OFF    = SPART_OFF + (size_t)B_ * KC4 * C_ * 4;
  constexpr size_t U2_OFF    = U1_OFF  + (size_t)B_ * C_ * 4;
  constexpr size_t ABF_OFF   = U2_OFF  + (size_t)B_ * C_ * 4;       // 1 MB

  float* G     = (float*)(ws + G_OFF);
  float* T1    = (float*)(ws + T1_OFF);
  float* L     = (float*)(ws + L_OFF);
  float* w2t   = (float*)(ws + W2T_OFF);
  float* spart = (float*)(ws + SPART_OFF);
  float* u1    = (float*)(ws + U1_OFF);
  float* u2    = (float*)(ws + U2_OFF);
  unsigned short* Abf = (unsigned short*)(ws + ABF_OFF);

  k_transpose<<<64, 256, 0, stream>>>(w2, w2t);
  k_gram     <<<256, 512, 0, stream>>>(x, gpart, spart);
  k_reduce   <<<512, 256, 0, stream>>>(gpart, G);
  k_u        <<<B_, 256, 0, stream>>>(w1, w2, spart, u1, u2);
  k_smallmm  <<<dim3(32, B_), 256, 0, stream>>>(w1, 0, G, C_ * C_, T1, C_ * C_);
  k_smallmm  <<<dim3(32, B_), 256, 0, stream>>>(T1, C_ * C_, w2t, 0, L, C_ * C_);
  k_softmax  <<<dim3(C_, B_), 256, 0, stream>>>(L, b1, b2, u1, u2, Abf);
  k_av       <<<dim3(NPIX / 64 * B_), 512, 0, stream>>>(Abf, x, out);
}